// Round 5
// baseline (1083.259 us; speedup 1.0000x reference)
//
#include <hip/hip_runtime.h>
#include <hip/hip_bf16.h>

typedef __bf16 bf16x8 __attribute__((ext_vector_type(8)));
typedef __bf16 bf16x4 __attribute__((ext_vector_type(4)));
typedef float floatx4 __attribute__((ext_vector_type(4)));

#define MFMA16(a, b, c) __builtin_amdgcn_mfma_f32_16x16x32_bf16((a), (b), (c), 0, 0, 0)

// async 16B/lane global->LDS. lds base must be wave-uniform; HW adds lane*16.
#define GLOAD16(g, l) __builtin_amdgcn_global_load_lds( \
    (const __attribute__((address_space(1))) unsigned int*)(g), \
    (__attribute__((address_space(3))) unsigned int*)(l), 16, 0, 0)

static constexpr int DM = 2048, NH = 16, HD = 128, BATCH = 4, SEQ = 2048;
static constexpr int MROWS = BATCH * SEQ;  // 8192
static constexpr float SCALE = 0.08838834764831845f;  // 1/sqrt(128)
static constexpr float PMAX = 3.0f;  // fixed softmax shift (validated: absmax 4.9e-4)

static constexpr size_t XE = (size_t)MROWS * DM;  // 16.78M
static constexpr size_t WE = (size_t)DM * DM;     // 4.19M

// ---------------------------------------------------------------------------
// Fused f32->bf16 convert: x then Wq,Wk,Wv,Wo into one contiguous dst.
// ---------------------------------------------------------------------------
__global__ __launch_bounds__(256) void cvt_all(
    const float* __restrict__ x, const float* __restrict__ Wq,
    const float* __restrict__ Wk, const float* __restrict__ Wv,
    const float* __restrict__ Wo, __bf16* __restrict__ dst) {
  const size_t total = XE + 4 * WE;
  size_t stride = (size_t)gridDim.x * 256 * 8;
  for (size_t i = ((size_t)blockIdx.x * 256 + threadIdx.x) * 8; i < total; i += stride) {
    const float* src;
    size_t off;
    if (i < XE) { src = x; off = i; }
    else {
      size_t j = i - XE;
      int seg = (int)(j / WE);
      off = j - (size_t)seg * WE;
      src = seg == 0 ? Wq : (seg == 1 ? Wk : (seg == 2 ? Wv : Wo));
    }
    float4 a = *reinterpret_cast<const float4*>(src + off);
    float4 b = *reinterpret_cast<const float4*>(src + off + 4);
    bf16x8 r;
    r[0] = (__bf16)a.x; r[1] = (__bf16)a.y; r[2] = (__bf16)a.z; r[3] = (__bf16)a.w;
    r[4] = (__bf16)b.x; r[5] = (__bf16)b.y; r[6] = (__bf16)b.z; r[7] = (__bf16)b.w;
    *reinterpret_cast<bf16x8*>(dst + i) = r;
  }
}

// ---------------------------------------------------------------------------
// GEMM v2 core: block tile 256(M)x128(N), BK=64, 4 waves (2x2), wave tile
// 128x64. W (B-operand) fragments load DIRECT from global (b128/lane,
// identical addrs across wave pairs + across M-blocks -> L1/L2 hits,
// W col-tiles XCD-resident via grid layout). Only A is LDS-staged
// (GLOAD16, XOR swizzle -> 0 bank conflicts, proven R3).
// LDS demand: 48KB/154cyc = 312 B/cyc vs ~170 eff -> predicted ~50% MfmaUtil.
// ---------------------------------------------------------------------------
__device__ __forceinline__ void gemm256_core(
    const __bf16* __restrict__ A, const __bf16* __restrict__ W,
    unsigned short* sA, int tm, int tn, floatx4 (&acc)[8][4]) {
  const int tid = threadIdx.x;
  const int wave = tid >> 6, lane = tid & 63;
  const int q = lane >> 4, ml = lane & 15;
  const int waveM = (wave >> 1) * 128, waveN = (wave & 1) * 64;
  const int lrow = lane >> 3, cdst = lane & 7;
  const int csrc = cdst ^ lrow;

  const __bf16* wbase = W + (size_t)(tn + waveN + ml) * DM + q * 8;

  for (int k0 = 0; k0 < DM; k0 += 64) {
    __syncthreads();  // prior iter's aF reads complete before overwrite
    // W frags for both k32-steps, direct global (latency overlaps A staging)
    bf16x8 bF[2][4];
#pragma unroll
    for (int s = 0; s < 2; ++s)
#pragma unroll
      for (int ct = 0; ct < 4; ++ct)
        bF[s][ct] = *reinterpret_cast<const bf16x8*>(
            wbase + (size_t)ct * 16 * DM + k0 + s * 32);
    // A staging: 256 rows x 64, 8 rounds of 4KB
#pragma unroll
    for (int i = 0; i < 8; ++i) {
      int r0 = i * 32 + wave * 8;
      GLOAD16(A + (size_t)(tm + r0 + lrow) * DM + k0 + csrc * 8, &sA[r0 * 64]);
    }
    __syncthreads();  // staging (and bF) landed
#pragma unroll
    for (int s = 0; s < 2; ++s) {
      bf16x8 aF[8];
#pragma unroll
      for (int t = 0; t < 8; ++t)
        aF[t] = *reinterpret_cast<const bf16x8*>(
            &sA[(waveM + t * 16 + ml) * 64 + (((s * 4 + q) ^ (ml & 7)) * 8)]);
#pragma unroll
      for (int rt = 0; rt < 8; ++rt)
#pragma unroll
        for (int ct = 0; ct < 4; ++ct)
          acc[rt][ct] = MFMA16(aF[rt], bF[s][ct], acc[rt][ct]);
    }
  }
}

// ---------------------------------------------------------------------------
// Fused QKV projection: grid (48, 32). bx>>4 selects q/k/v; XCD = bx%8 so
// each XCD touches 6 W col-tiles (3MB, L2-resident).
// q,k -> head-major [B,H,T,HD]; v -> transposed [B,H,HD,T].
// ---------------------------------------------------------------------------
__global__ __launch_bounds__(256, 2) void qkv_gemm(
    const __bf16* __restrict__ X,
    const __bf16* __restrict__ Wq, const __bf16* __restrict__ Wk,
    const __bf16* __restrict__ Wv,
    const float* __restrict__ bq, const float* __restrict__ bk,
    const float* __restrict__ bv,
    __bf16* __restrict__ qh, __bf16* __restrict__ kh, __bf16* __restrict__ vt) {
  __shared__ unsigned short sA[256 * 64];
  const int which = blockIdx.x >> 4;
  const int tn = (blockIdx.x & 15) * 128;
  const int tm = blockIdx.y * 256;
  const __bf16* W = which == 0 ? Wq : (which == 1 ? Wk : Wv);
  const float* bias = which == 0 ? bq : (which == 1 ? bk : bv);

  floatx4 acc[8][4] = {};
  gemm256_core(X, W, sA, tm, tn, acc);

  const int tid = threadIdx.x, wave = tid >> 6, lane = tid & 63;
  const int q = lane >> 4, ml = lane & 15;
  const int waveM = (wave >> 1) * 128, waveN = (wave & 1) * 64;
#pragma unroll
  for (int ct = 0; ct < 4; ++ct) {
    int n = tn + waveN + ct * 16 + ml;
    float bv_ = bias[n];
    int h = n >> 7, d = n & 127;
#pragma unroll
    for (int rt = 0; rt < 8; ++rt) {
      int m0 = tm + waveM + rt * 16 + q * 4;
      int b = m0 >> 11, t = m0 & 2047;
      if (which < 2) {
        __bf16* dst = which == 0 ? qh : kh;
#pragma unroll
        for (int r = 0; r < 4; ++r)
          dst[((size_t)(b * 16 + h) * SEQ + t + r) * HD + d] = (__bf16)(acc[rt][ct][r] + bv_);
      } else {
        bf16x4 pk;
#pragma unroll
        for (int r = 0; r < 4; ++r) pk[r] = (__bf16)(acc[rt][ct][r] + bv_);
        *reinterpret_cast<bf16x4*>(vt + (size_t)((b * 16 + h) * 128 + d) * SEQ + t) = pk;
      }
    }
  }
}

// ---------------------------------------------------------------------------
// Output projection: grid (16, 32). A bf16 row-major, W bf16, out f32.
// ---------------------------------------------------------------------------
__global__ __launch_bounds__(256, 2) void proj_gemm(
    const __bf16* __restrict__ A, const __bf16* __restrict__ W,
    const float* __restrict__ bias, float* __restrict__ out) {
  __shared__ unsigned short sA[256 * 64];
  const int tn = blockIdx.x * 128;
  const int tm = blockIdx.y * 256;

  floatx4 acc[8][4] = {};
  gemm256_core(A, W, sA, tm, tn, acc);

  const int tid = threadIdx.x, wave = tid >> 6, lane = tid & 63;
  const int q = lane >> 4, ml = lane & 15;
  const int waveM = (wave >> 1) * 128, waveN = (wave & 1) * 64;
#pragma unroll
  for (int ct = 0; ct < 4; ++ct) {
    int n = tn + waveN + ct * 16 + ml;
    float bv_ = bias[n];
#pragma unroll
    for (int rt = 0; rt < 8; ++rt) {
      int m0 = tm + waveM + rt * 16 + q * 4;
#pragma unroll
      for (int r = 0; r < 4; ++r)
        out[(size_t)(m0 + r) * DM + n] = acc[rt][ct][r] + bv_;
    }
  }
}

// ---------------------------------------------------------------------------
// Flash attention v3 — BARRIER-FREE K-loop. grid (B*H, SEQ/128), 256 thr =
// 4 waves x 32 q-rows. K-frags and V-frags load DIRECT from global to
// registers (head-major K rows / V^T rows are contiguous in k; identical
// addrs across waves -> L1/L2 hits; per-XCD bh affinity keeps K,V resident).
// Only P round-trips through LDS (wave-private rows -> no __syncthreads).
// Fixed-max softmax (proven R3/R4).
// ---------------------------------------------------------------------------
__global__ __launch_bounds__(256, 2) void mha_attn(
    const __bf16* __restrict__ Q, const __bf16* __restrict__ Kg,
    const __bf16* __restrict__ Vt, __bf16* __restrict__ O) {
  __shared__ unsigned short sP[128 * 72];

  const int tid = threadIdx.x;
  const int bh = blockIdx.x;                // fast dim -> XCD affinity
  const int t0 = blockIdx.y * 128;
  const int wave = tid >> 6, lane = tid & 63;
  const int q = lane >> 4, ml = lane & 15;
  const int wrow = wave * 32;

  // Q frags in registers: 2 q-tiles x 4 k-steps
  bf16x8 qf[2][4];
  {
    const __bf16* qbase = Q + ((size_t)bh * SEQ + t0 + wrow) * HD;
#pragma unroll
    for (int qt = 0; qt < 2; ++qt)
#pragma unroll
      for (int s = 0; s < 4; ++s)
        qf[qt][s] = *reinterpret_cast<const bf16x8*>(
            qbase + (size_t)(qt * 16 + ml) * HD + s * 32 + q * 8);
  }

  floatx4 oacc[2][8] = {};
  float lsum[2][4] = {};

  const __bf16* kbase = Kg + (size_t)bh * SEQ * HD + q * 8;
  const __bf16* vbase = Vt + (size_t)bh * HD * SEQ + q * 8;

  for (int kt = 0; kt < SEQ / 64; ++kt) {
    const int key0 = kt * 64;

    // S = Q K^T : 2 q-tiles x 4 key-tiles, K-frags direct from global
    floatx4 sacc[2][4] = {};
#pragma unroll
    for (int s = 0; s < 4; ++s) {
      bf16x8 kf[4];
#pragma unroll
      for (int ct = 0; ct < 4; ++ct)
        kf[ct] = *reinterpret_cast<const bf16x8*>(
            kbase + (size_t)(key0 + ct * 16 + ml) * HD + s * 32);
#pragma unroll
      for (int qt = 0; qt < 2; ++qt)
#pragma unroll
        for (int ct = 0; ct < 4; ++ct)
          sacc[qt][ct] = MFMA16(qf[qt][s], kf[ct], sacc[qt][ct]);
    }

    // fixed-max softmax numerator + local row-sums + P -> LDS (A-layout rows)
#pragma unroll
    for (int qt = 0; qt < 2; ++qt)
#pragma unroll
      for (int ct = 0; ct < 4; ++ct)
#pragma unroll
        for (int r = 0; r < 4; ++r) {
          float p = __expf(fmaf(sacc[qt][ct][r], SCALE, -PMAX));
          lsum[qt][r] += p;
          __bf16 pb = (__bf16)p;
          sP[(wrow + qt * 16 + q * 4 + r) * 72 + ct * 16 + ml] =
              __builtin_bit_cast(unsigned short, pb);
        }

    // O += P V : V-frags direct from global (V^T rows contiguous in key)
#pragma unroll
    for (int s = 0; s < 2; ++s) {
      bf16x8 pf[2];
#pragma unroll
      for (int qt = 0; qt < 2; ++qt)
        pf[qt] = *reinterpret_cast<const bf16x8*>(
            &sP[(wrow + qt * 16 + ml) * 72 + s * 32 + q * 8]);
#pragma unroll
      for (int ot = 0; ot < 8; ++ot) {
        bf16x8 vf = *reinterpret_cast<const bf16x8*>(
            vbase + (size_t)(ot * 16 + ml) * SEQ + key0 + s * 32);
#pragma unroll
        for (int qt = 0; qt < 2; ++qt)
          oacc[qt][ot] = MFMA16(pf[qt], vf, oacc[qt][ot]);
      }
    }
  }

  // epilogue: reduce row-sums across the 16 key-lanes, write O [B*T, DM]
  const int b = bh >> 4, h = bh & 15;
#pragma unroll
  for (int qt = 0; qt < 2; ++qt) {
#pragma unroll
    for (int r = 0; r < 4; ++r) {
      float s = lsum[qt][r];
      s += __shfl_xor(s, 1); s += __shfl_xor(s, 2);
      s += __shfl_xor(s, 4); s += __shfl_xor(s, 8);
      lsum[qt][r] = 1.0f / s;
    }
    __bf16* obase = O + ((size_t)b * SEQ + t0 + wrow + qt * 16) * DM + h * HD;
#pragma unroll
    for (int ot = 0; ot < 8; ++ot) {
      int d = ot * 16 + ml;
#pragma unroll
      for (int r = 0; r < 4; ++r)
        obase[(size_t)(q * 4 + r) * DM + d] = (__bf16)(oacc[qt][ot][r] * lsum[qt][r]);
    }
  }
}

// ---------------------------------------------------------------------------
// Fallback slow GEMM (small-ws safety only; R4-proven).
// mode 0: row-major out (f32 if out_f32). mode 1: vt. mode 2: head-major q/k.
// ---------------------------------------------------------------------------
__device__ inline bf16x8 ld8s(const float* p) {
  float4 a = *reinterpret_cast<const float4*>(p);
  float4 b = *reinterpret_cast<const float4*>(p + 4);
  bf16x8 r;
  r[0] = (__bf16)a.x; r[1] = (__bf16)a.y; r[2] = (__bf16)a.z; r[3] = (__bf16)a.w;
  r[4] = (__bf16)b.x; r[5] = (__bf16)b.y; r[6] = (__bf16)b.z; r[7] = (__bf16)b.w;
  return r;
}
__device__ inline bf16x8 ld8s(const __bf16* p) {
  int4 v = *reinterpret_cast<const int4*>(p);
  return __builtin_bit_cast(bf16x8, v);
}

template <typename TA>
__global__ __launch_bounds__(256) void gemm_slow(
    const TA* __restrict__ A, const float* __restrict__ W,
    const float* __restrict__ bias, void* __restrict__ C, int mode, int out_f32) {
  __shared__ unsigned short sA[128 * 72];
  __shared__ unsigned short sW[128 * 72];
  const int tid = threadIdx.x;
  const int tn = blockIdx.x * 128, tm = blockIdx.y * 128;
  const int wave = tid >> 6, lane = tid & 63;
  const int q = lane >> 4, ml = lane & 15;
  const int waveM = (wave >> 1) * 64, waveN = (wave & 1) * 64;
  const int srow = tid >> 3, sc8 = tid & 7;
  floatx4 acc[4][4] = {};
  for (int k0 = 0; k0 < DM; k0 += 64) {
    bf16x8 va[4], vb[4];
#pragma unroll
    for (int i = 0; i < 4; ++i) {
      int row = srow + 32 * i;
      va[i] = ld8s(A + (size_t)(tm + row) * DM + k0 + sc8 * 8);
      vb[i] = ld8s(W + (size_t)(tn + row) * DM + k0 + sc8 * 8);
    }
    __syncthreads();
#pragma unroll
    for (int i = 0; i < 4; ++i) {
      int row = srow + 32 * i;
      *reinterpret_cast<int4*>(&sA[row * 72 + sc8 * 8]) = __builtin_bit_cast(int4, va[i]);
      *reinterpret_cast<int4*>(&sW[row * 72 + sc8 * 8]) = __builtin_bit_cast(int4, vb[i]);
    }
    __syncthreads();
#pragma unroll
    for (int s = 0; s < 2; ++s) {
      bf16x8 aF[4], bF[4];
#pragma unroll
      for (int t = 0; t < 4; ++t)
        aF[t] = *reinterpret_cast<const bf16x8*>(&sA[(waveM + t * 16 + ml) * 72 + s * 32 + q * 8]);
#pragma unroll
      for (int t = 0; t < 4; ++t)
        bF[t] = *reinterpret_cast<const bf16x8*>(&sW[(waveN + t * 16 + ml) * 72 + s * 32 + q * 8]);
#pragma unroll
      for (int rt = 0; rt < 4; ++rt)
#pragma unroll
        for (int ct = 0; ct < 4; ++ct)
          acc[rt][ct] = MFMA16(aF[rt], bF[ct], acc[rt][ct]);
    }
  }
#pragma unroll
  for (int ct = 0; ct < 4; ++ct) {
    int n = tn + waveN + ct * 16 + ml;
    float bv = bias[n];
    int h = n >> 7, d = n & 127;
#pragma unroll
    for (int rt = 0; rt < 4; ++rt) {
      int m0 = tm + waveM + rt * 16 + q * 4;
      int b = m0 >> 11, t = m0 & 2047;
      if (mode == 0) {
        if (out_f32) {
#pragma unroll
          for (int r = 0; r < 4; ++r)
            ((float*)C)[(size_t)(m0 + r) * DM + n] = acc[rt][ct][r] + bv;
        } else {
#pragma unroll
          for (int r = 0; r < 4; ++r)
            ((__bf16*)C)[(size_t)(m0 + r) * DM + n] = (__bf16)(acc[rt][ct][r] + bv);
        }
      } else if (mode == 1) {
        bf16x4 pk;
#pragma unroll
        for (int r = 0; r < 4; ++r) pk[r] = (__bf16)(acc[rt][ct][r] + bv);
        *reinterpret_cast<bf16x4*>((__bf16*)C + (size_t)((b * 16 + h) * 128 + d) * SEQ + t) = pk;
      } else {
#pragma unroll
        for (int r = 0; r < 4; ++r)
          ((__bf16*)C)[((size_t)(b * 16 + h) * SEQ + t + r) * HD + d] =
              (__bf16)(acc[rt][ct][r] + bv);
      }
    }
  }
}

// ---------------------------------------------------------------------------
extern "C" void kernel_launch(void* const* d_in, const int* in_sizes, int n_in,
                              void* d_out, int out_size, void* d_ws, size_t ws_size,
                              hipStream_t stream) {
  const float* x  = (const float*)d_in[0];
  const float* Wq = (const float*)d_in[1]; const float* bq = (const float*)d_in[2];
  const float* Wk = (const float*)d_in[3]; const float* bk = (const float*)d_in[4];
  const float* Wv = (const float*)d_in[5]; const float* bv = (const float*)d_in[6];
  const float* Wo = (const float*)d_in[7]; const float* bo = (const float*)d_in[8];

  const size_t needA = 64 + 2 * (4 * XE + 4 * WE);  // ~167.8 MB
  dim3 gq(48, 32), gp(16, 32), ga(BATCH * NH, SEQ / 128);

  if (ws_size >= needA + 256) {
    // xc also serves as aw (x dead after QKV)
    __bf16* xc  = (__bf16*)((char*)d_ws + 64);
    __bf16* Wqc = xc + XE;
    __bf16* Wkc = Wqc + WE;
    __bf16* Wvc = Wkc + WE;
    __bf16* Woc = Wvc + WE;
    __bf16* qh  = Woc + WE;
    __bf16* kh  = qh + XE;
    __bf16* vt  = kh + XE;
    __bf16* aw  = xc;

    cvt_all<<<4096, 256, 0, stream>>>(x, Wq, Wk, Wv, Wo, xc);
    qkv_gemm<<<gq, 256, 0, stream>>>(xc, Wqc, Wkc, Wvc, bq, bk, bv, qh, kh, vt);
    mha_attn<<<ga, 256, 0, stream>>>(qh, kh, vt, aw);
    proj_gemm<<<gp, 256, 0, stream>>>(aw, Woc, bo, (float*)d_out);
  } else {
    // fallback: no weight conversion, slow VGPR-convert GEMMs
    dim3 gs(16, 64);
    __bf16* qh = (__bf16*)((char*)d_ws + 64);
    __bf16* kh = qh + XE;
    __bf16* vt = kh + XE;
    __bf16* aw = vt + XE;
    gemm_slow<float><<<gs, 256, 0, stream>>>(x, Wq, bq, qh, 2, 0);
    gemm_slow<float><<<gs, 256, 0, stream>>>(x, Wk, bk, kh, 2, 0);
    gemm_slow<float><<<gs, 256, 0, stream>>>(x, Wv, bv, vt, 1, 0);
    mha_attn<<<ga, 256, 0, stream>>>(qh, kh, vt, aw);
    gemm_slow<__bf16><<<gs, 256, 0, stream>>>(aw, Wo, bo, d_out, 0, 1);
  }
}